// Round 11
// baseline (204.484 us; speedup 1.0000x reference)
//
#include <hip/hip_runtime.h>
#include <math.h>

#define BB 8
#define NN 4096
#define MM 4000
#define KK 5
#define NPAD 4096
#define SS 4608                        // sorted array stride (4096 + 512 sentinel pad)
#define SCAN_BLOCKS (64 * BB * 2)      // 1024

#define ACC_ROT    0
#define ACC_TRANS  1
#define ACC_ALIGN  2
#define ACC_DISP   3
#define ACC_DEFORM 4
#define ACC_LAP    5
#define ACC_RMSE   6   // 8 entries
#define ACC_COUNT  14

#define INFF __int_as_float(0x7F800000)
#define SENT_X 1e9f
#define SENT_W 3e18f

__device__ __forceinline__ float waveReduceSum(float v) {
#pragma unroll
    for (int off = 32; off > 0; off >>= 1) v += __shfl_down(v, off, 64);
    return v;
}

// Scan groups of 8 wave-uniform candidates from global (s_load path, r5-proven).
// Score = cn - 2 q.c (shifted by -|q|^2, ranking-invariant). PACK: index in low
// 12 mantissa bits (tie -> smaller index). SELF: mask own point. EXCL: mask the
// pass-1 range [exlo, exhi) (those candidates enter the merge via md[8]).
template<bool SELF, bool PACK, bool EXCL>
__device__ __forceinline__ void scanG(const float4* __restrict__ S, int ws, int ng,
                                      int exlo, int exhi,
                                      float ca, float cb, float cc, int q,
                                      float& b0, float& b1, float& b2,
                                      float& b3, float& b4) {
    for (int g = 0; g < ng; ++g) {
        int bb = __builtin_amdgcn_readfirstlane(ws + (g << 3));
        float4 C[8];
#pragma unroll
        for (int j = 0; j < 8; ++j) C[j] = S[bb + j];
#pragma unroll
        for (int j = 0; j < 8; ++j) {
            int m = bb + j;
            float sc = fmaf(C[j].x, ca, fmaf(C[j].y, cb, fmaf(C[j].z, cc, C[j].w)));
            float v = sc;
            if (PACK) {
                unsigned pk = (__float_as_uint(sc) & 0xFFFFF000u) | (unsigned)(m & 0xFFF);
                v = __uint_as_float(pk);
            }
            if (SELF) v = (m == q) ? INFF : v;
            if (EXCL) v = (m >= exlo && m < exhi) ? INFF : v;
            float n0 = fminf(b0, v);
            float n1 = __builtin_amdgcn_fmed3f(v, b0, b1);
            float n2 = __builtin_amdgcn_fmed3f(v, b1, b2);
            float n3 = __builtin_amdgcn_fmed3f(v, b2, b3);
            float n4 = __builtin_amdgcn_fmed3f(v, b3, b4);
            b0 = n0; b1 = n1; b2 = n2; b3 = n3; b4 = n4;
        }
    }
}

// Vectorized 2-step binary search over sorted .x keys (wave-uniform result).
// UPPER=false: first index with key >= t. UPPER=true: first index with key > t.
template<bool UPPER>
__device__ __forceinline__ int bsearch64(const float4* __restrict__ S, float t, int lane) {
    float k1 = S[lane << 6].x;
    unsigned long long m1 = __ballot(UPPER ? (k1 <= t) : (k1 < t));
    int c1 = __popcll(m1);
    int seg = c1 > 0 ? c1 - 1 : 0;
    float k2 = S[(seg << 6) + lane].x;
    unsigned long long m2 = __ballot(UPPER ? (k2 <= t) : (k2 < t));
    return (seg << 6) + __popcll(m2);
}

__device__ __forceinline__ void merge8(const float (*md)[64][6], int l, float* m5) {
    int pp0 = 0, pp1 = 0, pp2 = 0, pp3 = 0, pp4 = 0, pp5 = 0, pp6 = 0, pp7 = 0;
#pragma unroll
    for (int k = 0; k < KK; ++k) {
        float best = INFF; int bw = 0;
        { float d = md[0][l][pp0]; if (d < best) { best = d; bw = 0; } }
        { float d = md[1][l][pp1]; if (d < best) { best = d; bw = 1; } }
        { float d = md[2][l][pp2]; if (d < best) { best = d; bw = 2; } }
        { float d = md[3][l][pp3]; if (d < best) { best = d; bw = 3; } }
        { float d = md[4][l][pp4]; if (d < best) { best = d; bw = 4; } }
        { float d = md[5][l][pp5]; if (d < best) { best = d; bw = 5; } }
        { float d = md[6][l][pp6]; if (d < best) { best = d; bw = 6; } }
        { float d = md[7][l][pp7]; if (d < best) { best = d; bw = 7; } }
        m5[k] = best;
        pp0 += (bw == 0); pp1 += (bw == 1); pp2 += (bw == 2); pp3 += (bw == 3);
        pp4 += (bw == 4); pp5 += (bw == 5); pp6 += (bw == 6); pp7 += (bw == 7);
    }
}

// K1: Y_rigid/X/X_hat padded float4+norm, rmse/disp partials, rot/trans losses.
__global__ void k_prep(const float* __restrict__ Y, const float* __restrict__ X,
                       const float* __restrict__ Rp, const float* __restrict__ tp,
                       const float* __restrict__ Rg, const float* __restrict__ tg,
                       const float* __restrict__ dl, const float* __restrict__ Xh,
                       float4* __restrict__ YrP, float4* __restrict__ XP,
                       float4* __restrict__ XhP, float* __restrict__ acc) {
    int b = blockIdx.x >> 4;
    int n = ((blockIdx.x & 15) << 8) + threadIdx.x;
    size_t base = ((size_t)b * NN + n) * 3;
    float yx = Y[base + 0], yy = Y[base + 1], yz = Y[base + 2];

    float rp[9], rg[9], tpv[3], tgv[3];
#pragma unroll
    for (int i = 0; i < 9; ++i) { rp[i] = Rp[b * 9 + i]; rg[i] = Rg[b * 9 + i]; }
#pragma unroll
    for (int i = 0; i < 3; ++i) { tpv[i] = tp[b * 3 + i]; tgv[i] = tg[b * 3 + i]; }

    float p[3], dr2 = 0.f;
#pragma unroll
    for (int k = 0; k < 3; ++k) {
        float pv = fmaf(yx, rp[k * 3 + 0], fmaf(yy, rp[k * 3 + 1], fmaf(yz, rp[k * 3 + 2], tpv[k])));
        float gv = fmaf(yx, rg[k * 3 + 0], fmaf(yy, rg[k * 3 + 1], fmaf(yz, rg[k * 3 + 2], tgv[k])));
        p[k] = pv;
        float dd = pv - gv;
        dr2 = fmaf(dd, dd, dr2);
    }
    YrP[(size_t)b * NPAD + n] =
        make_float4(p[0], p[1], p[2], fmaf(p[0], p[0], fmaf(p[1], p[1], p[2] * p[2])));

    float4 xe;
    if (n < MM) {
        size_t xb = ((size_t)b * MM + n) * 3;
        float x0 = X[xb + 0], x1 = X[xb + 1], x2 = X[xb + 2];
        xe = make_float4(x0, x1, x2, fmaf(x0, x0, fmaf(x1, x1, x2 * x2)));
    } else {
        xe = make_float4(SENT_X, SENT_X, SENT_X, SENT_W);
    }
    XP[(size_t)b * NPAD + n] = xe;

    float h0 = Xh[base + 0], h1 = Xh[base + 1], h2 = Xh[base + 2];
    XhP[(size_t)b * NPAD + n] =
        make_float4(h0, h1, h2, fmaf(h0, h0, fmaf(h1, h1, h2 * h2)));

    float d0 = dl[base + 0], d1 = dl[base + 1], d2 = dl[base + 2];
    float dsq = d0 * d0 + d1 * d1 + d2 * d2;

    dr2 = waveReduceSum(dr2);
    dsq = waveReduceSum(dsq);
    if ((threadIdx.x & 63) == 0) {
        atomicAdd(&acc[ACC_RMSE + b], dr2);
        atomicAdd(&acc[ACC_DISP], dsq);
    }

    if (threadIdx.x == 0 && (blockIdx.x & 15) == 0) {
        float tr = 0.f;
#pragma unroll
        for (int i = 0; i < 9; ++i) tr += rp[i] * rg[i];
        float c = (tr - 1.f) * 0.5f;
        c = fminf(fmaxf(c, -1.f + 1e-7f), 1.f - 1e-7f);
        float dx = tpv[0] - tgv[0], dy = tpv[1] - tgv[1], dz = tpv[2] - tgv[2];
        atomicAdd(&acc[ACC_ROT], acosf(c));
        atomicAdd(&acc[ACC_TRANS], sqrtf(dx * dx + dy * dy + dz * dz));
    }
}

// K2: per-(batch,array) LDS bitonic sort by x; emit sorted float4 + orig index.
__global__ void k_sort(const float4* __restrict__ YrP, const float4* __restrict__ XP,
                       const float4* __restrict__ XhP,
                       float4* __restrict__ SYr, float4* __restrict__ SX,
                       float4* __restrict__ SXh, int* __restrict__ sidx) {
    __shared__ unsigned long long keys[NPAD];
    int b = blockIdx.x, aid = blockIdx.y, t = threadIdx.x;
    const float4* src = (aid == 0 ? YrP : aid == 1 ? XP : XhP) + (size_t)b * NPAD;
    float4* dst = (aid == 0 ? SYr : aid == 1 ? SX : SXh) + (size_t)b * SS;
    int* sid = sidx + ((size_t)aid * BB + b) * SS;

    for (int i = t; i < NPAD; i += 512) {
        unsigned u = __float_as_uint(src[i].x);
        u ^= (u >> 31) ? 0xFFFFFFFFu : 0x80000000u;   // sortable float bits
        keys[i] = ((unsigned long long)u << 32) | (unsigned)i;
    }
    __syncthreads();
    for (int k = 2; k <= NPAD; k <<= 1) {
        for (int j = k >> 1; j > 0; j >>= 1) {
            for (int i = t; i < NPAD; i += 512) {
                int l = i ^ j;
                if (l > i) {
                    unsigned long long a = keys[i], c = keys[l];
                    bool asc = ((i & k) == 0);
                    if ((a > c) == asc) { keys[i] = c; keys[l] = a; }
                }
            }
            __syncthreads();
        }
    }
    for (int i = t; i < NPAD; i += 512) {
        int oi = (int)(keys[i] & 0xFFFFFFFFull);
        dst[i] = src[oi];
        sid[i] = oi;
    }
    for (int i = NPAD + t; i < SS; i += 512) {
        dst[i] = make_float4(SENT_X, SENT_X, SENT_X, SENT_W);
        sid[i] = 0;
    }
}

__device__ void finalize(const float* acc, float* out) {
    float a[ACC_COUNT];
#pragma unroll
    for (int i = 0; i < ACC_COUNT; ++i)
        a[i] = __hip_atomic_load(&acc[i], __ATOMIC_RELAXED, __HIP_MEMORY_SCOPE_AGENT);
    float L_rot = a[ACC_ROT] / BB;
    float L_trans = a[ACC_TRANS] / BB;
    float L_rmse = 0.f;
#pragma unroll
    for (int b = 0; b < BB; ++b) L_rmse += sqrtf(a[ACC_RMSE + b] / NN);
    L_rmse /= BB;
    float L_align = a[ACC_ALIGN] / ((float)BB * NN * KK);
    float L_disp = a[ACC_DISP] / ((float)BB * NN);
    float L_def = a[ACC_DEFORM] / ((float)BB * NN * KK);
    float L_lap = a[ACC_LAP] / ((float)BB * NN);
    float rigid = L_rot + L_trans + L_rmse;
    float nr = L_align + 0.01f * L_disp + 0.1f * L_def + 0.1f * L_lap;
    out[0] = rigid + nr; out[1] = rigid; out[2] = nr;
    out[3] = L_rot; out[4] = L_trans; out[5] = L_rmse;
    out[6] = L_align; out[7] = L_disp; out[8] = L_def; out[9] = L_lap;
}

#define MS(W) { float d = md[W][l][pp##W]; if (d < best) { best = d; bw = W; } }
#define MA()  { pp0 += (bw == 0); pp1 += (bw == 1); pp2 += (bw == 2); pp3 += (bw == 3); \
                pp4 += (bw == 4); pp5 += (bw == 5); pp6 += (bw == 6); pp7 += (bw == 7); \
                pp8 += (bw == 8); }

// K3: window-pruned exact kNN. blockIdx = (query-group of 64, batch, mode).
// mode 0 = align (queries SXh, candidates SX); mode 1 = knn (SYr both).
__global__ __launch_bounds__(512, 4) void k_scan(const float4* __restrict__ SYr,
                                                 const float4* __restrict__ SX,
                                                 const float4* __restrict__ SXh,
                                                 const int* __restrict__ sidx,
                                                 const float* __restrict__ Xh,
                                                 const float* __restrict__ dl,
                                                 float* __restrict__ acc,
                                                 unsigned* __restrict__ doneCnt,
                                                 float* __restrict__ out) {
    __shared__ float md[9][64][6];
    int tid = threadIdx.x, wave = tid >> 6, lane = tid & 63;
    int qg = blockIdx.x, b = blockIdx.y, mode = blockIdx.z;
    int qbase = qg << 6, qpos = qbase + lane;

    const float4* S  = (mode ? SYr : SX)  + (size_t)b * SS;
    const float4* QA = (mode ? SYr : SXh) + (size_t)b * SS;
    float4 qd = QA[qpos];
    float ca = -2.f * qd.x, cb = -2.f * qd.y, cc = -2.f * qd.z;

    // ---- pass 1: fixed sorted-x neighborhood -> d5 upper bound ----
    int w1lo, w1hi;
    if (mode) {
        w1lo = qbase - 128 > 0 ? qbase - 128 : 0;
        w1hi = qbase + 192 < NN ? qbase + 192 : NN;
    } else {
        int plo = (qbase * MM) >> 12;
        int phi = (((qbase + 63) * MM) >> 12) + 1;
        w1lo = plo - 128 > 0 ? plo - 128 : 0;
        w1hi = phi + 128 < NN ? phi + 128 : NN;
    }
    int ng1 = (w1hi - w1lo + 63) >> 6;       // groups of 8 per wave
    int per1 = ng1 << 3;
    int p1end = w1lo + (per1 << 3);          // exact scanned set = [w1lo, p1end)
    int ws1 = w1lo + wave * per1;

    float b0 = INFF, b1 = INFF, b2 = INFF, b3 = INFF, b4 = INFF;
    bool sf1 = mode && (ws1 < qbase + 64) && (ws1 + per1 > qbase);
    if (sf1)       scanG<true,  true,  false>(S, ws1, ng1, 0, 0, ca, cb, cc, qpos, b0, b1, b2, b3, b4);
    else if (mode) scanG<false, true,  false>(S, ws1, ng1, 0, 0, ca, cb, cc, qpos, b0, b1, b2, b3, b4);
    else           scanG<false, false, false>(S, ws1, ng1, 0, 0, ca, cb, cc, qpos, b0, b1, b2, b3, b4);

    md[wave][lane][0] = b0; md[wave][lane][1] = b1; md[wave][lane][2] = b2;
    md[wave][lane][3] = b3; md[wave][lane][4] = b4; md[wave][lane][5] = INFF;
    __syncthreads();

    float m5[KK];
    merge8(md, lane, m5);
    float ub = m5[KK - 1];
    if (mode) {                               // undo packed-mantissa truncation, sign-correct
        unsigned u = __float_as_uint(ub);
        u = (ub >= 0.f) ? (u | 0xFFFu) : (u & ~0xFFFu);
        ub = __uint_as_float(u);
    }
    float R = ub + qd.w;                      // true d5^2 upper bound for this query
#pragma unroll
    for (int off = 32; off > 0; off >>= 1) R = fmaxf(R, __shfl_down(R, off, 64));
    R = __shfl(R, 0, 64);
    R = fmaxf(R, 0.f) * 1.001f + 1e-5f;       // inflation: rounding + order-stat safety
    float r = sqrtf(R);
    float tlo = __shfl(qd.x, 0, 64) - r;
    float thi = __shfl(qd.x, 63, 64) + r;

    if (wave == 0) {                          // pass-1 merged list = 9th merge input
        md[8][lane][0] = m5[0]; md[8][lane][1] = m5[1]; md[8][lane][2] = m5[2];
        md[8][lane][3] = m5[3]; md[8][lane][4] = m5[4]; md[8][lane][5] = INFF;
    }
    __syncthreads();

    // ---- pass 2: exact window scan, pass-1 range excluded ----
    int wlo2 = bsearch64<false>(S, tlo, lane);
    int whi2 = bsearch64<true>(S, thi, lane);
    int cnt2 = whi2 - wlo2; if (cnt2 < 0) cnt2 = 0;
    int ng2 = (cnt2 + 63) >> 6;
    int per2 = ng2 << 3;
    int ws2 = wlo2 + wave * per2;

    b0 = b1 = b2 = b3 = b4 = INFF;
    bool sf2 = mode && (ws2 < qbase + 64) && (ws2 + per2 > qbase);
    if (mode) {
        if (sf2) scanG<true,  true, true>(S, ws2, ng2, w1lo, p1end, ca, cb, cc, qpos, b0, b1, b2, b3, b4);
        else     scanG<false, true, true>(S, ws2, ng2, w1lo, p1end, ca, cb, cc, qpos, b0, b1, b2, b3, b4);
    } else       scanG<false, false, true>(S, ws2, ng2, w1lo, p1end, ca, cb, cc, qpos, b0, b1, b2, b3, b4);

    md[wave][lane][0] = b0; md[wave][lane][1] = b1; md[wave][lane][2] = b2;
    md[wave][lane][3] = b3; md[wave][lane][4] = b4; md[wave][lane][5] = INFF;
    __syncthreads();

    if (tid < 64) {                           // wave 0: 9-way merge + loss terms
        int l = tid;
        int pp0 = 0, pp1 = 0, pp2 = 0, pp3 = 0, pp4 = 0, pp5 = 0, pp6 = 0, pp7 = 0, pp8 = 0;
        if (mode == 0) {
            float qn = qd.w;
            float s = 0.f;
#pragma unroll
            for (int k = 0; k < KK; ++k) {
                float best = INFF; int bw = 0;
                MS(0) MS(1) MS(2) MS(3) MS(4) MS(5) MS(6) MS(7) MS(8)
                s += fmaxf(best + qn, 0.f);
                MA()
            }
            s = waveReduceSum(s);
            if (l == 0) atomicAdd(&acc[ACC_ALIGN], s);
        } else {
            int si[KK];
#pragma unroll
            for (int k = 0; k < KK; ++k) {
                float best = INFF; int bw = 0;
                MS(0) MS(1) MS(2) MS(3) MS(4) MS(5) MS(6) MS(7) MS(8)
                si[k] = (int)(__float_as_uint(best) & 0xFFFu);
                MA()
            }
            const float4* SYb = SYr + (size_t)b * SS;
            const int* sId = sidx + (size_t)b * SS;   // array 0 = Yr
            int oq = sId[qpos];
            const float* xh = Xh + (size_t)b * NN * 3;
            const float* dlb = dl + (size_t)b * NN * 3;
            float xnx = xh[oq * 3 + 0], xny = xh[oq * 3 + 1], xnz = xh[oq * 3 + 2];
            float dnx = dlb[oq * 3 + 0], dny = dlb[oq * 3 + 1], dnz = dlb[oq * 3 + 2];

            float def = 0.f, sx = 0.f, sy = 0.f, sz = 0.f;
#pragma unroll
            for (int k = 0; k < KK; ++k) {
                int pos = si[k];
                float4 yj = SYb[pos];
                int oi = sId[pos];
                float ex = (xh[oi * 3 + 0] - xnx) - (yj.x - qd.x);
                float ey = (xh[oi * 3 + 1] - xny) - (yj.y - qd.y);
                float ez = (xh[oi * 3 + 2] - xnz) - (yj.z - qd.z);
                def += ex * ex + ey * ey + ez * ez;
                sx += dlb[oi * 3 + 0]; sy += dlb[oi * 3 + 1]; sz += dlb[oi * 3 + 2];
            }
            float lx = dnx - sx / 5.f, ly = dny - sy / 5.f, lz = dnz - sz / 5.f;
            float lap = lx * lx + ly * ly + lz * lz;

            def = waveReduceSum(def);
            lap = waveReduceSum(lap);
            if (l == 0) {
                atomicAdd(&acc[ACC_DEFORM], def);
                atomicAdd(&acc[ACC_LAP], lap);
            }
        }
    }
    __syncthreads();
    if (tid == 0) {
        __threadfence();
        unsigned t = __hip_atomic_fetch_add(doneCnt, 1u, __ATOMIC_ACQ_REL,
                                            __HIP_MEMORY_SCOPE_AGENT);
        if (t == SCAN_BLOCKS - 1) finalize(acc, out);
    }
}

extern "C" void kernel_launch(void* const* d_in, const int* in_sizes, int n_in,
                              void* d_out, int out_size, void* d_ws, size_t ws_size,
                              hipStream_t stream) {
    const float* Y  = (const float*)d_in[0];
    const float* X  = (const float*)d_in[1];
    const float* Rp = (const float*)d_in[2];
    const float* tp = (const float*)d_in[3];
    const float* Rg = (const float*)d_in[4];
    const float* tg = (const float*)d_in[5];
    const float* Xh = (const float*)d_in[6];
    const float* dl = (const float*)d_in[7];
    float* out = (float*)d_out;

    char* w = (char*)d_ws;
    float*    acc     = (float*)w;
    unsigned* doneCnt = (unsigned*)(w + 64);
    float4*   YrP     = (float4*)(w + 512);
    float4*   XP      = YrP + (size_t)BB * NPAD;
    float4*   XhP     = XP  + (size_t)BB * NPAD;
    float4*   SYr     = XhP + (size_t)BB * NPAD;
    float4*   SX      = SYr + (size_t)BB * SS;
    float4*   SXh     = SX  + (size_t)BB * SS;
    int*      sidx    = (int*)(SXh + (size_t)BB * SS);   // 3 arrays x BB x SS

    hipMemsetAsync(d_ws, 0, 512, stream);
    hipLaunchKernelGGL(k_prep, dim3(BB * NN / 256), dim3(256), 0, stream,
                       Y, X, Rp, tp, Rg, tg, dl, Xh, YrP, XP, XhP, acc);
    hipLaunchKernelGGL(k_sort, dim3(BB, 3), dim3(512), 0, stream,
                       YrP, XP, XhP, SYr, SX, SXh, sidx);
    hipLaunchKernelGGL(k_scan, dim3(64, BB, 2), dim3(512), 0, stream,
                       SYr, SX, SXh, sidx, Xh, dl, acc, doneCnt, out);
}

// Round 12
// 118.500 us; speedup vs baseline: 1.7256x; 1.7256x over previous
//
#include <hip/hip_runtime.h>
#include <math.h>

#define BB 8
#define NN 4096
#define MM 4000
#define KK 5
#define NWAVE 8
#define QG 128                        // queries per block (2 per lane)
#define CH 512                        // candidates per wave-chunk
#define NPAD 4096
#define SCAN_BLOCKS ((NN / QG) * BB * 2)   // 32*8*2 = 512

#define ACC_ROT    0
#define ACC_TRANS  1
#define ACC_ALIGN  2
#define ACC_DISP   3
#define ACC_DEFORM 4
#define ACC_LAP    5
#define ACC_RMSE   6   // 8 entries
#define ACC_COUNT  14

#define INFF __int_as_float(0x7F800000)

__device__ __forceinline__ float waveReduceSum(float v) {
#pragma unroll
    for (int off = 32; off > 0; off >>= 1) v += __shfl_down(v, off, 64);
    return v;
}

// Insert v into sorted (b0<=..<=b4): 1 min + 4 independent med3 (proven r6+).
// Score shifted by -|q|^2 (ranking-invariant). PACK: candidate index in low
// 12 mantissa bits (tie -> smaller index, = top_k semantics).
template<bool SELF, bool PACK>
__device__ __forceinline__ void proc1(float4 c, int midx, int q,
                                      float ca, float cbq, float cc,
                                      float& b0, float& b1, float& b2,
                                      float& b3, float& b4) {
    float sc = fmaf(c.x, ca, fmaf(c.y, cbq, fmaf(c.z, cc, c.w)));
    float v;
    if (PACK) {
        unsigned pk = (__float_as_uint(sc) & 0xFFFFF000u) | (unsigned)midx;
        v = __uint_as_float(pk);
        if (SELF) v = (midx == q) ? INFF : v;
    } else {
        v = sc;
    }
    float n0 = fminf(b0, v);
    float n1 = __builtin_amdgcn_fmed3f(v, b0, b1);
    float n2 = __builtin_amdgcn_fmed3f(v, b1, b2);
    float n3 = __builtin_amdgcn_fmed3f(v, b2, b3);
    float n4 = __builtin_amdgcn_fmed3f(v, b3, b4);
    b0 = n0; b1 = n1; b2 = n2; b3 = n3; b4 = n4;
}

// Scan a CH-candidate chunk for TWO queries per lane, candidates fetched as
// uniform-address global_load_dwordx4 (one broadcast transaction serves 128
// pairs; L1/L2-resident). 8-deep A/B ping-pong: the compiler's partial
// vmcnt(N) waits keep the next group's loads in flight under ~320 cycles of
// VALU work — the pipelineable path that SMEM (lgkmcnt drain) and DS (shared
// LDS pipe) could not provide.
template<bool SELF, bool PACK>
__device__ __forceinline__ void scanGlob2(const float4* __restrict__ cb, int tc,
                                          float a0, float b0c, float c0, int q0,
                                          float a1, float b1c, float c1, int q1,
                                          float& x0, float& x1, float& x2,
                                          float& x3, float& x4,
                                          float& y0, float& y1, float& y2,
                                          float& y3, float& y4) {
    float4 A[8], B[8];
#pragma unroll
    for (int j = 0; j < 8; ++j) A[j] = cb[tc + j];

    for (int t0 = 0; t0 < CH; t0 += 16) {
#pragma unroll
        for (int j = 0; j < 8; ++j) B[j] = cb[tc + t0 + 8 + j];
#pragma unroll
        for (int j = 0; j < 8; ++j) {
            proc1<SELF, PACK>(A[j], tc + t0 + j, q0, a0, b0c, c0, x0, x1, x2, x3, x4);
            proc1<SELF, PACK>(A[j], tc + t0 + j, q1, a1, b1c, c1, y0, y1, y2, y3, y4);
        }
        if (t0 + 16 < CH) {
#pragma unroll
            for (int j = 0; j < 8; ++j) A[j] = cb[tc + t0 + 16 + j];
        }
#pragma unroll
        for (int j = 0; j < 8; ++j) {
            proc1<SELF, PACK>(B[j], tc + t0 + 8 + j, q0, a0, b0c, c0, x0, x1, x2, x3, x4);
            proc1<SELF, PACK>(B[j], tc + t0 + 8 + j, q1, a1, b1c, c1, y0, y1, y2, y3, y4);
        }
    }
}

// K1: Y_rigid (padded float4 + norm), X padded float4 + norm, rmse/disp
// partials, rot/trans losses.
__global__ void k_prep(const float* __restrict__ Y, const float* __restrict__ X,
                       const float* __restrict__ Rp, const float* __restrict__ tp,
                       const float* __restrict__ Rg, const float* __restrict__ tg,
                       const float* __restrict__ dl,
                       float4* __restrict__ YrP, float4* __restrict__ XP,
                       float* __restrict__ acc) {
    int b = blockIdx.x >> 4;
    int n = ((blockIdx.x & 15) << 8) + threadIdx.x;
    size_t base = ((size_t)b * NN + n) * 3;
    float yx = Y[base + 0], yy = Y[base + 1], yz = Y[base + 2];

    float rp[9], rg[9], tpv[3], tgv[3];
#pragma unroll
    for (int i = 0; i < 9; ++i) { rp[i] = Rp[b * 9 + i]; rg[i] = Rg[b * 9 + i]; }
#pragma unroll
    for (int i = 0; i < 3; ++i) { tpv[i] = tp[b * 3 + i]; tgv[i] = tg[b * 3 + i]; }

    float p[3], dr2 = 0.f;
#pragma unroll
    for (int k = 0; k < 3; ++k) {
        float pv = fmaf(yx, rp[k * 3 + 0], fmaf(yy, rp[k * 3 + 1], fmaf(yz, rp[k * 3 + 2], tpv[k])));
        float gv = fmaf(yx, rg[k * 3 + 0], fmaf(yy, rg[k * 3 + 1], fmaf(yz, rg[k * 3 + 2], tgv[k])));
        p[k] = pv;
        float dd = pv - gv;
        dr2 = fmaf(dd, dd, dr2);
    }
    YrP[(size_t)b * NPAD + n] =
        make_float4(p[0], p[1], p[2], fmaf(p[0], p[0], fmaf(p[1], p[1], p[2] * p[2])));

    float4 xe;
    if (n < MM) {
        size_t xb = ((size_t)b * MM + n) * 3;
        float x0 = X[xb + 0], x1 = X[xb + 1], x2 = X[xb + 2];
        xe = make_float4(x0, x1, x2, fmaf(x0, x0, fmaf(x1, x1, x2 * x2)));
    } else {
        xe = make_float4(0.f, 0.f, 0.f, INFF);
    }
    XP[(size_t)b * NPAD + n] = xe;

    float d0 = dl[base + 0], d1 = dl[base + 1], d2 = dl[base + 2];
    float dsq = d0 * d0 + d1 * d1 + d2 * d2;

    dr2 = waveReduceSum(dr2);
    dsq = waveReduceSum(dsq);
    if ((threadIdx.x & 63) == 0) {
        atomicAdd(&acc[ACC_RMSE + b], dr2);
        atomicAdd(&acc[ACC_DISP], dsq);
    }

    if (threadIdx.x == 0 && (blockIdx.x & 15) == 0) {
        float tr = 0.f;
#pragma unroll
        for (int i = 0; i < 9; ++i) tr += rp[i] * rg[i];
        float c = (tr - 1.f) * 0.5f;
        c = fminf(fmaxf(c, -1.f + 1e-7f), 1.f - 1e-7f);
        float dx = tpv[0] - tgv[0], dy = tpv[1] - tgv[1], dz = tpv[2] - tgv[2];
        atomicAdd(&acc[ACC_ROT], acosf(c));
        atomicAdd(&acc[ACC_TRANS], sqrtf(dx * dx + dy * dy + dz * dz));
    }
}

__device__ void finalize(const float* acc, float* out) {
    float a[ACC_COUNT];
#pragma unroll
    for (int i = 0; i < ACC_COUNT; ++i)
        a[i] = __hip_atomic_load(&acc[i], __ATOMIC_RELAXED, __HIP_MEMORY_SCOPE_AGENT);
    float L_rot = a[ACC_ROT] / BB;
    float L_trans = a[ACC_TRANS] / BB;
    float L_rmse = 0.f;
#pragma unroll
    for (int b = 0; b < BB; ++b) L_rmse += sqrtf(a[ACC_RMSE + b] / NN);
    L_rmse /= BB;
    float L_align = a[ACC_ALIGN] / ((float)BB * NN * KK);
    float L_disp = a[ACC_DISP] / ((float)BB * NN);
    float L_def = a[ACC_DEFORM] / ((float)BB * NN * KK);
    float L_lap = a[ACC_LAP] / ((float)BB * NN);
    float rigid = L_rot + L_trans + L_rmse;
    float nr = L_align + 0.01f * L_disp + 0.1f * L_def + 0.1f * L_lap;
    out[0] = rigid + nr; out[1] = rigid; out[2] = nr;
    out[3] = L_rot; out[4] = L_trans; out[5] = L_rmse;
    out[6] = L_align; out[7] = L_disp; out[8] = L_def; out[9] = L_lap;
}

#define MERGE_STEP(W) { float d = md[W][l][pp##W]; if (d < best) { best = d; bw = W; } }
#define MERGE_ADV()  { pp0 += (bw == 0); pp1 += (bw == 1); pp2 += (bw == 2); pp3 += (bw == 3); \
                       pp4 += (bw == 4); pp5 += (bw == 5); pp6 += (bw == 6); pp7 += (bw == 7); }

// K2: fused scan, global-broadcast candidates, Q=2/lane. blockIdx.z = mode
// (0=align on XP, 1=knn on YrP). LDS = merge partials only (24 KB).
__global__ __launch_bounds__(512, 4) void k_scan(const float* __restrict__ Xh,
                                                 const float4* __restrict__ XP,
                                                 const float4* __restrict__ YrP,
                                                 const float* __restrict__ dl,
                                                 float* __restrict__ acc,
                                                 unsigned* __restrict__ doneCnt,
                                                 float* __restrict__ out) {
    __shared__ float md[NWAVE][QG][6];             // 24 KB merge partials
    int tid = threadIdx.x, wave = tid >> 6, lane = tid & 63;
    int qg = blockIdx.x, b = blockIdx.y, mode = blockIdx.z;
    int q0 = qg * QG + lane, q1 = q0 + 64;

    const float4* cbG = (mode == 0 ? XP : YrP) + (size_t)b * NPAD;

    float qx0, qy0, qz0, qx1, qy1, qz1;
    if (mode == 0) {
        size_t a0 = ((size_t)b * NN + q0) * 3;
        size_t a1 = ((size_t)b * NN + q1) * 3;
        qx0 = Xh[a0 + 0]; qy0 = Xh[a0 + 1]; qz0 = Xh[a0 + 2];
        qx1 = Xh[a1 + 0]; qy1 = Xh[a1 + 1]; qz1 = Xh[a1 + 2];
    } else {
        float4 p0 = cbG[q0], p1 = cbG[q1];
        qx0 = p0.x; qy0 = p0.y; qz0 = p0.z;
        qx1 = p1.x; qy1 = p1.y; qz1 = p1.z;
    }

    float x0 = INFF, x1 = INFF, x2 = INFF, x3 = INFF, x4 = INFF;
    float y0 = INFF, y1 = INFF, y2 = INFF, y3 = INFF, y4 = INFF;
    int tc = wave * CH;
    if (mode == 0) {
        scanGlob2<false, false>(cbG, tc,
                                -2.f * qx0, -2.f * qy0, -2.f * qz0, 0,
                                -2.f * qx1, -2.f * qy1, -2.f * qz1, 0,
                                x0, x1, x2, x3, x4, y0, y1, y2, y3, y4);
    } else if (wave == (qg >> 2)) {                // chunk containing this block's queries
        scanGlob2<true, true>(cbG, tc,
                              -2.f * qx0, -2.f * qy0, -2.f * qz0, q0,
                              -2.f * qx1, -2.f * qy1, -2.f * qz1, q1,
                              x0, x1, x2, x3, x4, y0, y1, y2, y3, y4);
    } else {
        scanGlob2<false, true>(cbG, tc,
                               -2.f * qx0, -2.f * qy0, -2.f * qz0, q0,
                               -2.f * qx1, -2.f * qy1, -2.f * qz1, q1,
                               x0, x1, x2, x3, x4, y0, y1, y2, y3, y4);
    }

    md[wave][lane][0] = x0; md[wave][lane][1] = x1; md[wave][lane][2] = x2;
    md[wave][lane][3] = x3; md[wave][lane][4] = x4; md[wave][lane][5] = INFF;
    md[wave][lane + 64][0] = y0; md[wave][lane + 64][1] = y1;
    md[wave][lane + 64][2] = y2; md[wave][lane + 64][3] = y3;
    md[wave][lane + 64][4] = y4; md[wave][lane + 64][5] = INFF;
    __syncthreads();

    if (tid < QG) {
        int l = tid;
        int q = qg * QG + l;
        int pp0 = 0, pp1 = 0, pp2 = 0, pp3 = 0, pp4 = 0, pp5 = 0, pp6 = 0, pp7 = 0;
        if (mode == 0) {
            size_t a0 = ((size_t)b * NN + q) * 3;
            float qx = Xh[a0 + 0], qy = Xh[a0 + 1], qz = Xh[a0 + 2];
            float qn = fmaf(qx, qx, fmaf(qy, qy, qz * qz));
            float s = 0.f;
#pragma unroll
            for (int k = 0; k < KK; ++k) {
                float best = INFF; int bw = 0;
                MERGE_STEP(0) MERGE_STEP(1) MERGE_STEP(2) MERGE_STEP(3)
                MERGE_STEP(4) MERGE_STEP(5) MERGE_STEP(6) MERGE_STEP(7)
                s += fmaxf(best + qn, 0.f);
                MERGE_ADV()
            }
            s = waveReduceSum(s);
            if ((l & 63) == 0) atomicAdd(&acc[ACC_ALIGN], s);
        } else {
            int si[KK];
#pragma unroll
            for (int k = 0; k < KK; ++k) {
                float best = INFF; int bw = 0;
                MERGE_STEP(0) MERGE_STEP(1) MERGE_STEP(2) MERGE_STEP(3)
                MERGE_STEP(4) MERGE_STEP(5) MERGE_STEP(6) MERGE_STEP(7)
                si[k] = (int)(__float_as_uint(best) & 0xFFFu);
                MERGE_ADV()
            }
            float4 qp = cbG[q];
            const float* xh = Xh + (size_t)b * NN * 3;
            const float* dlb = dl + (size_t)b * NN * 3;
            float xnx = xh[q * 3 + 0], xny = xh[q * 3 + 1], xnz = xh[q * 3 + 2];
            float dnx = dlb[q * 3 + 0], dny = dlb[q * 3 + 1], dnz = dlb[q * 3 + 2];

            float def = 0.f, sx = 0.f, sy = 0.f, sz = 0.f;
#pragma unroll
            for (int k = 0; k < KK; ++k) {
                int n = si[k];
                float4 yj = cbG[n];                // L2-resident gather
                float ex = (xh[n * 3 + 0] - xnx) - (yj.x - qp.x);
                float ey = (xh[n * 3 + 1] - xny) - (yj.y - qp.y);
                float ez = (xh[n * 3 + 2] - xnz) - (yj.z - qp.z);
                def += ex * ex + ey * ey + ez * ez;
                sx += dlb[n * 3 + 0]; sy += dlb[n * 3 + 1]; sz += dlb[n * 3 + 2];
            }
            float lx = dnx - sx / 5.f, ly = dny - sy / 5.f, lz = dnz - sz / 5.f;
            float lap = lx * lx + ly * ly + lz * lz;

            def = waveReduceSum(def);
            lap = waveReduceSum(lap);
            if ((l & 63) == 0) {
                atomicAdd(&acc[ACC_DEFORM], def);
                atomicAdd(&acc[ACC_LAP], lap);
            }
        }
    }
    __syncthreads();
    if (tid == 0) {
        __threadfence();
        unsigned t = __hip_atomic_fetch_add(doneCnt, 1u, __ATOMIC_ACQ_REL,
                                            __HIP_MEMORY_SCOPE_AGENT);
        if (t == SCAN_BLOCKS - 1) finalize(acc, out);
    }
}

extern "C" void kernel_launch(void* const* d_in, const int* in_sizes, int n_in,
                              void* d_out, int out_size, void* d_ws, size_t ws_size,
                              hipStream_t stream) {
    const float* Y  = (const float*)d_in[0];
    const float* X  = (const float*)d_in[1];
    const float* Rp = (const float*)d_in[2];
    const float* tp = (const float*)d_in[3];
    const float* Rg = (const float*)d_in[4];
    const float* tg = (const float*)d_in[5];
    const float* Xh = (const float*)d_in[6];
    const float* dl = (const float*)d_in[7];
    float* out = (float*)d_out;

    float*    acc     = (float*)d_ws;                            // 14 floats
    unsigned* doneCnt = (unsigned*)((char*)d_ws + 64);
    float4*   YrP     = (float4*)((char*)d_ws + 512);            // 512 KB
    float4*   XP      = YrP + (size_t)BB * NPAD;                 // 512 KB

    hipMemsetAsync(d_ws, 0, 512, stream);
    hipLaunchKernelGGL(k_prep, dim3(BB * NN / 256), dim3(256), 0, stream,
                       Y, X, Rp, tp, Rg, tg, dl, YrP, XP, acc);
    hipLaunchKernelGGL(k_scan, dim3(NN / QG, BB, 2), dim3(512), 0, stream,
                       Xh, XP, YrP, dl, acc, doneCnt, out);
}

// Round 13
// 115.190 us; speedup vs baseline: 1.7752x; 1.0287x over previous
//
#include <hip/hip_runtime.h>
#include <math.h>

#define BB 8
#define NN 4096
#define MM 4000
#define KK 5
#define NWAVE 8
#define QG 128                        // queries per block (2 per lane)
#define CH 256                        // candidates per wave-chunk (half: 8*256=2048)
#define HSZ 2048                      // candidates per block (one half)
#define NPAD 4096
#define MQ_BLK 256
#define M_BLOCKS (BB * NN / MQ_BLK)   // 128

#define ACC_ROT    0
#define ACC_TRANS  1
#define ACC_ALIGN  2
#define ACC_DISP   3
#define ACC_DEFORM 4
#define ACC_LAP    5
#define ACC_RMSE   6   // 8 entries
#define ACC_COUNT  14

#define INFF __int_as_float(0x7F800000)

__device__ __forceinline__ float waveReduceSum(float v) {
#pragma unroll
    for (int off = 32; off > 0; off >>= 1) v += __shfl_down(v, off, 64);
    return v;
}

// Insert v into sorted (b0<=..<=b4): 1 min + 4 independent med3 (proven r6+).
// Score shifted by -|q|^2 (ranking-invariant). PACK: candidate index in low
// 12 mantissa bits (tie -> smaller index, = top_k semantics).
template<bool SELF, bool PACK>
__device__ __forceinline__ void proc1(float4 c, int midx, int q,
                                      float ca, float cbq, float cc,
                                      float& b0, float& b1, float& b2,
                                      float& b3, float& b4) {
    float sc = fmaf(c.x, ca, fmaf(c.y, cbq, fmaf(c.z, cc, c.w)));
    float v;
    if (PACK) {
        unsigned pk = (__float_as_uint(sc) & 0xFFFFF000u) | (unsigned)midx;
        v = __uint_as_float(pk);
        if (SELF) v = (midx == q) ? INFF : v;
    } else {
        v = sc;
    }
    float n0 = fminf(b0, v);
    float n1 = __builtin_amdgcn_fmed3f(v, b0, b1);
    float n2 = __builtin_amdgcn_fmed3f(v, b1, b2);
    float n3 = __builtin_amdgcn_fmed3f(v, b2, b3);
    float n4 = __builtin_amdgcn_fmed3f(v, b3, b4);
    b0 = n0; b1 = n1; b2 = n2; b3 = n3; b4 = n4;
}

// Scan a CH-candidate LDS chunk (LDS-local base tl, global index base tg) for
// TWO queries per lane. One broadcast ds_read_b128 serves 128 pairs; 4-deep
// A/B ping-pong (32 VGPR, r10-proven: 52 VGPR total, no spill).
template<bool SELF, bool PACK>
__device__ __forceinline__ void scanLDS2(const float4* lc, int tl, int tg,
                                         float a0, float b0c, float c0, int q0,
                                         float a1, float b1c, float c1, int q1,
                                         float& x0, float& x1, float& x2,
                                         float& x3, float& x4,
                                         float& y0, float& y1, float& y2,
                                         float& y3, float& y4) {
    float4 A[4], B[4];
#pragma unroll
    for (int j = 0; j < 4; ++j) A[j] = lc[tl + j];

    for (int t0 = 0; t0 < CH; t0 += 8) {
#pragma unroll
        for (int j = 0; j < 4; ++j) B[j] = lc[tl + t0 + 4 + j];
#pragma unroll
        for (int j = 0; j < 4; ++j) {
            proc1<SELF, PACK>(A[j], tg + t0 + j, q0, a0, b0c, c0, x0, x1, x2, x3, x4);
            proc1<SELF, PACK>(A[j], tg + t0 + j, q1, a1, b1c, c1, y0, y1, y2, y3, y4);
        }
        if (t0 + 8 < CH) {
#pragma unroll
            for (int j = 0; j < 4; ++j) A[j] = lc[tl + t0 + 8 + j];
        }
#pragma unroll
        for (int j = 0; j < 4; ++j) {
            proc1<SELF, PACK>(B[j], tg + t0 + 4 + j, q0, a0, b0c, c0, x0, x1, x2, x3, x4);
            proc1<SELF, PACK>(B[j], tg + t0 + 4 + j, q1, a1, b1c, c1, y0, y1, y2, y3, y4);
        }
    }
}

// K1: Y_rigid (padded float4 + norm), X padded float4 + norm, rmse/disp
// partials, rot/trans losses.
__global__ void k_prep(const float* __restrict__ Y, const float* __restrict__ X,
                       const float* __restrict__ Rp, const float* __restrict__ tp,
                       const float* __restrict__ Rg, const float* __restrict__ tg,
                       const float* __restrict__ dl,
                       float4* __restrict__ YrP, float4* __restrict__ XP,
                       float* __restrict__ acc) {
    int b = blockIdx.x >> 4;
    int n = ((blockIdx.x & 15) << 8) + threadIdx.x;
    size_t base = ((size_t)b * NN + n) * 3;
    float yx = Y[base + 0], yy = Y[base + 1], yz = Y[base + 2];

    float rp[9], rg[9], tpv[3], tgv[3];
#pragma unroll
    for (int i = 0; i < 9; ++i) { rp[i] = Rp[b * 9 + i]; rg[i] = Rg[b * 9 + i]; }
#pragma unroll
    for (int i = 0; i < 3; ++i) { tpv[i] = tp[b * 3 + i]; tgv[i] = tg[b * 3 + i]; }

    float p[3], dr2 = 0.f;
#pragma unroll
    for (int k = 0; k < 3; ++k) {
        float pv = fmaf(yx, rp[k * 3 + 0], fmaf(yy, rp[k * 3 + 1], fmaf(yz, rp[k * 3 + 2], tpv[k])));
        float gv = fmaf(yx, rg[k * 3 + 0], fmaf(yy, rg[k * 3 + 1], fmaf(yz, rg[k * 3 + 2], tgv[k])));
        p[k] = pv;
        float dd = pv - gv;
        dr2 = fmaf(dd, dd, dr2);
    }
    YrP[(size_t)b * NPAD + n] =
        make_float4(p[0], p[1], p[2], fmaf(p[0], p[0], fmaf(p[1], p[1], p[2] * p[2])));

    float4 xe;
    if (n < MM) {
        size_t xb = ((size_t)b * MM + n) * 3;
        float x0 = X[xb + 0], x1 = X[xb + 1], x2 = X[xb + 2];
        xe = make_float4(x0, x1, x2, fmaf(x0, x0, fmaf(x1, x1, x2 * x2)));
    } else {
        xe = make_float4(0.f, 0.f, 0.f, INFF);
    }
    XP[(size_t)b * NPAD + n] = xe;

    float d0 = dl[base + 0], d1 = dl[base + 1], d2 = dl[base + 2];
    float dsq = d0 * d0 + d1 * d1 + d2 * d2;

    dr2 = waveReduceSum(dr2);
    dsq = waveReduceSum(dsq);
    if ((threadIdx.x & 63) == 0) {
        atomicAdd(&acc[ACC_RMSE + b], dr2);
        atomicAdd(&acc[ACC_DISP], dsq);
    }

    if (threadIdx.x == 0 && (blockIdx.x & 15) == 0) {
        float tr = 0.f;
#pragma unroll
        for (int i = 0; i < 9; ++i) tr += rp[i] * rg[i];
        float c = (tr - 1.f) * 0.5f;
        c = fminf(fmaxf(c, -1.f + 1e-7f), 1.f - 1e-7f);
        float dx = tpv[0] - tgv[0], dy = tpv[1] - tgv[1], dz = tpv[2] - tgv[2];
        atomicAdd(&acc[ACC_ROT], acosf(c));
        atomicAdd(&acc[ACC_TRANS], sqrtf(dx * dx + dy * dy + dz * dz));
    }
}

#define MERGE_STEP(W) { float d = mdp[((W) * QG + l) * 6 + pp##W]; if (d < best) { best = d; bw = W; } }
#define MERGE_ADV()  { pp0 += (bw == 0); pp1 += (bw == 1); pp2 += (bw == 2); pp3 += (bw == 3); \
                       pp4 += (bw == 4); pp5 += (bw == 5); pp6 += (bw == 6); pp7 += (bw == 7); }

// K2: scan. blockIdx.z = mode*2+half. Stage 2048 candidates (32 KB -> 3
// blocks/CU, 24 waves/CU vs r10's 64 KB/2-block cap), 8 waves x 256-candidate
// chunks, Q=2/lane; 8-way in-block merge (partial array aliases the stage);
// per-half sorted-5 partial to global.
__global__ __launch_bounds__(512, 6) void k_scan(const float* __restrict__ Xh,
                                                 const float4* __restrict__ XP,
                                                 const float4* __restrict__ YrP,
                                                 float* __restrict__ pa,
                                                 float* __restrict__ pk) {
    __shared__ float4 lsbuf[HSZ];                  // 32 KB: candidates, then merge partials
    float* mdp = (float*)lsbuf;
    int tid = threadIdx.x, wave = tid >> 6, lane = tid & 63;
    int qg = blockIdx.x, b = blockIdx.y;
    int half = blockIdx.z & 1, mode = blockIdx.z >> 1;
    int q0 = qg * QG + lane, q1 = q0 + 64;

    const float4* cbG = (mode == 0 ? XP : YrP) + (size_t)b * NPAD;
#pragma unroll
    for (int i = 0; i < HSZ / 512; ++i)
        lsbuf[tid + i * 512] = cbG[half * HSZ + tid + i * 512];

    float qx0, qy0, qz0, qx1, qy1, qz1;
    if (mode == 0) {
        size_t a0 = ((size_t)b * NN + q0) * 3;
        size_t a1 = ((size_t)b * NN + q1) * 3;
        qx0 = Xh[a0 + 0]; qy0 = Xh[a0 + 1]; qz0 = Xh[a0 + 2];
        qx1 = Xh[a1 + 0]; qy1 = Xh[a1 + 1]; qz1 = Xh[a1 + 2];
    } else {
        float4 p0 = cbG[q0], p1 = cbG[q1];
        qx0 = p0.x; qy0 = p0.y; qz0 = p0.z;
        qx1 = p1.x; qy1 = p1.y; qz1 = p1.z;
    }
    __syncthreads();

    float x0 = INFF, x1 = INFF, x2 = INFF, x3 = INFF, x4 = INFF;
    float y0 = INFF, y1 = INFF, y2 = INFF, y3 = INFF, y4 = INFF;
    int tl = wave * CH;                            // LDS-local chunk base
    int tg = half * HSZ + tl;                      // global candidate base
    // block's 128 queries lie in one 256-wide chunk: half qg>>4, wave (qg>>1)&7
    bool hasSelf = (mode == 1) && (half == (qg >> 4)) && (wave == ((qg >> 1) & 7));
    if (mode == 0) {
        scanLDS2<false, false>(lsbuf, tl, tg,
                               -2.f * qx0, -2.f * qy0, -2.f * qz0, 0,
                               -2.f * qx1, -2.f * qy1, -2.f * qz1, 0,
                               x0, x1, x2, x3, x4, y0, y1, y2, y3, y4);
    } else if (hasSelf) {
        scanLDS2<true, true>(lsbuf, tl, tg,
                             -2.f * qx0, -2.f * qy0, -2.f * qz0, q0,
                             -2.f * qx1, -2.f * qy1, -2.f * qz1, q1,
                             x0, x1, x2, x3, x4, y0, y1, y2, y3, y4);
    } else {
        scanLDS2<false, true>(lsbuf, tl, tg,
                              -2.f * qx0, -2.f * qy0, -2.f * qz0, q0,
                              -2.f * qx1, -2.f * qy1, -2.f * qz1, q1,
                              x0, x1, x2, x3, x4, y0, y1, y2, y3, y4);
    }
    __syncthreads();                               // all scan reads of lsbuf done

    float* m0 = &mdp[(wave * QG + lane) * 6];
    m0[0] = x0; m0[1] = x1; m0[2] = x2; m0[3] = x3; m0[4] = x4; m0[5] = INFF;
    float* m1 = &mdp[(wave * QG + lane + 64) * 6];
    m1[0] = y0; m1[1] = y1; m1[2] = y2; m1[3] = y3; m1[4] = y4; m1[5] = INFF;
    __syncthreads();

    if (tid < QG) {
        int l = tid;
        int q = qg * QG + l;
        int pp0 = 0, pp1 = 0, pp2 = 0, pp3 = 0, pp4 = 0, pp5 = 0, pp6 = 0, pp7 = 0;
        float* dst = (mode == 0 ? pa : pk) + (((size_t)b * NN + q) * 2 + half) * 6;
#pragma unroll
        for (int k = 0; k < KK; ++k) {
            float best = INFF; int bw = 0;
            MERGE_STEP(0) MERGE_STEP(1) MERGE_STEP(2) MERGE_STEP(3)
            MERGE_STEP(4) MERGE_STEP(5) MERGE_STEP(6) MERGE_STEP(7)
            dst[k] = best;
            MERGE_ADV()
        }
        dst[5] = INFF;
    }
}

__device__ void finalize(const float* acc, float* out) {
    float a[ACC_COUNT];
#pragma unroll
    for (int i = 0; i < ACC_COUNT; ++i)
        a[i] = __hip_atomic_load(&acc[i], __ATOMIC_RELAXED, __HIP_MEMORY_SCOPE_AGENT);
    float L_rot = a[ACC_ROT] / BB;
    float L_trans = a[ACC_TRANS] / BB;
    float L_rmse = 0.f;
#pragma unroll
    for (int b = 0; b < BB; ++b) L_rmse += sqrtf(a[ACC_RMSE + b] / NN);
    L_rmse /= BB;
    float L_align = a[ACC_ALIGN] / ((float)BB * NN * KK);
    float L_disp = a[ACC_DISP] / ((float)BB * NN);
    float L_def = a[ACC_DEFORM] / ((float)BB * NN * KK);
    float L_lap = a[ACC_LAP] / ((float)BB * NN);
    float rigid = L_rot + L_trans + L_rmse;
    float nr = L_align + 0.01f * L_disp + 0.1f * L_def + 0.1f * L_lap;
    out[0] = rigid + nr; out[1] = rigid; out[2] = nr;
    out[3] = L_rot; out[4] = L_trans; out[5] = L_rmse;
    out[6] = L_align; out[7] = L_disp; out[8] = L_def; out[9] = L_lap;
}

// K3: fused 2-way merges (align + knn), deform/lap epilogue, finalize.
// Proven r6 (absmax 0.0).
__global__ void k_merge(const float4* __restrict__ YrP, const float* __restrict__ Xh,
                        const float* __restrict__ dl, const float* __restrict__ pa,
                        const float* __restrict__ pk, float* __restrict__ acc,
                        unsigned* __restrict__ doneCnt, float* __restrict__ out) {
    int gid = blockIdx.x * MQ_BLK + threadIdx.x;   // 0 .. B*N-1
    int b = gid >> 12, q = gid & (NN - 1);

    // --- align: merge two sorted partials, add |q|^2 back, clamp ---
    size_t qb = (size_t)gid * 3;
    float qhx = Xh[qb + 0], qhy = Xh[qb + 1], qhz = Xh[qb + 2];
    float qn = fmaf(qhx, qhx, fmaf(qhy, qhy, qhz * qhz));
    {
        const float* p0 = pa + (size_t)gid * 12;
        const float* p1 = p0 + 6;
        int i = 0, j = 0;
        float s = 0.f;
#pragma unroll
        for (int k = 0; k < KK; ++k) {
            float a = p0[i], c = p1[j];
            bool ta = (a <= c);                    // half0 first = smaller index
            s += fmaxf((ta ? a : c) + qn, 0.f);
            i += ta; j += !ta;
        }
        s = waveReduceSum(s);
        if ((threadIdx.x & 63) == 0) atomicAdd(&acc[ACC_ALIGN], s);
    }

    // --- knn: merge packed partials, deform/lap epilogue ---
    const float4* cb = YrP + (size_t)b * NPAD;
    float4 qp = cb[q];
    const float* p0 = pk + (size_t)gid * 12;
    const float* p1 = p0 + 6;
    int i = 0, j = 0;
    int si[KK];
#pragma unroll
    for (int k = 0; k < KK; ++k) {
        float a = p0[i], c = p1[j];
        bool ta = (a <= c);
        si[k] = (int)(__float_as_uint(ta ? a : c) & 0xFFFu);
        i += ta; j += !ta;
    }

    const float* xh = Xh + (size_t)b * NN * 3;
    const float* dlb = dl + (size_t)b * NN * 3;
    float xnx = xh[q * 3 + 0], xny = xh[q * 3 + 1], xnz = xh[q * 3 + 2];
    float dnx = dlb[q * 3 + 0], dny = dlb[q * 3 + 1], dnz = dlb[q * 3 + 2];

    float def = 0.f, sx = 0.f, sy = 0.f, sz = 0.f;
#pragma unroll
    for (int k = 0; k < KK; ++k) {
        int n = si[k];
        float4 yj = cb[n];
        float ex = (xh[n * 3 + 0] - xnx) - (yj.x - qp.x);
        float ey = (xh[n * 3 + 1] - xny) - (yj.y - qp.y);
        float ez = (xh[n * 3 + 2] - xnz) - (yj.z - qp.z);
        def += ex * ex + ey * ey + ez * ez;
        sx += dlb[n * 3 + 0]; sy += dlb[n * 3 + 1]; sz += dlb[n * 3 + 2];
    }
    float lx = dnx - sx / 5.f, ly = dny - sy / 5.f, lz = dnz - sz / 5.f;
    float lap = lx * lx + ly * ly + lz * lz;

    def = waveReduceSum(def);
    lap = waveReduceSum(lap);
    if ((threadIdx.x & 63) == 0) {
        atomicAdd(&acc[ACC_DEFORM], def);
        atomicAdd(&acc[ACC_LAP], lap);
    }
    __syncthreads();
    if (threadIdx.x == 0) {
        __threadfence();
        unsigned t = __hip_atomic_fetch_add(doneCnt, 1u, __ATOMIC_ACQ_REL,
                                            __HIP_MEMORY_SCOPE_AGENT);
        if (t == M_BLOCKS - 1) finalize(acc, out);
    }
}

extern "C" void kernel_launch(void* const* d_in, const int* in_sizes, int n_in,
                              void* d_out, int out_size, void* d_ws, size_t ws_size,
                              hipStream_t stream) {
    const float* Y  = (const float*)d_in[0];
    const float* X  = (const float*)d_in[1];
    const float* Rp = (const float*)d_in[2];
    const float* tp = (const float*)d_in[3];
    const float* Rg = (const float*)d_in[4];
    const float* tg = (const float*)d_in[5];
    const float* Xh = (const float*)d_in[6];
    const float* dl = (const float*)d_in[7];
    float* out = (float*)d_out;

    float*    acc     = (float*)d_ws;                            // 14 floats
    unsigned* doneCnt = (unsigned*)((char*)d_ws + 64);
    float4*   YrP     = (float4*)((char*)d_ws + 512);            // 512 KB
    float4*   XP      = YrP + (size_t)BB * NPAD;                 // 512 KB
    float*    pa      = (float*)(XP + (size_t)BB * NPAD);        // 1.5 MB
    float*    pk      = pa + (size_t)BB * NN * 12;               // 1.5 MB

    hipMemsetAsync(d_ws, 0, 512, stream);
    hipLaunchKernelGGL(k_prep, dim3(BB * NN / 256), dim3(256), 0, stream,
                       Y, X, Rp, tp, Rg, tg, dl, YrP, XP, acc);
    hipLaunchKernelGGL(k_scan, dim3(NN / QG, BB, 4), dim3(512), 0, stream,
                       Xh, XP, YrP, pa, pk);
    hipLaunchKernelGGL(k_merge, dim3(M_BLOCKS), dim3(MQ_BLK), 0, stream,
                       YrP, Xh, dl, pa, pk, acc, doneCnt, out);
}

// Round 14
// 108.052 us; speedup vs baseline: 1.8925x; 1.0661x over previous
//
#include <hip/hip_runtime.h>
#include <math.h>

#define BB 8
#define NN 4096
#define MM 4000
#define KK 5
#define NWAVE 8
#define QG 128                        // queries per block (2 per lane)
#define CH 256                        // candidates per wave-chunk
#define HSZ 2048                      // candidates staged per half
#define NPAD 4096
#define SCAN_BLOCKS ((NN / QG) * BB * 2)   // 32*8*2 = 512

#define ACC_ROT    0
#define ACC_TRANS  1
#define ACC_ALIGN  2
#define ACC_DISP   3
#define ACC_DEFORM 4
#define ACC_LAP    5
#define ACC_RMSE   6   // 8 entries
#define ACC_COUNT  14

#define INFF __int_as_float(0x7F800000)

__device__ __forceinline__ float waveReduceSum(float v) {
#pragma unroll
    for (int off = 32; off > 0; off >>= 1) v += __shfl_down(v, off, 64);
    return v;
}

// Insert v into sorted (b0<=..<=b4): 1 min + 4 independent med3 (proven r6+).
// Score shifted by -|q|^2 (ranking-invariant). PACK: candidate index in low
// 12 mantissa bits (tie -> smaller index, = top_k semantics).
template<bool SELF, bool PACK>
__device__ __forceinline__ void proc1(float4 c, int midx, int q,
                                      float ca, float cbq, float cc,
                                      float& b0, float& b1, float& b2,
                                      float& b3, float& b4) {
    float sc = fmaf(c.x, ca, fmaf(c.y, cbq, fmaf(c.z, cc, c.w)));
    float v;
    if (PACK) {
        unsigned pk = (__float_as_uint(sc) & 0xFFFFF000u) | (unsigned)midx;
        v = __uint_as_float(pk);
        if (SELF) v = (midx == q) ? INFF : v;
    } else {
        v = sc;
    }
    float n0 = fminf(b0, v);
    float n1 = __builtin_amdgcn_fmed3f(v, b0, b1);
    float n2 = __builtin_amdgcn_fmed3f(v, b1, b2);
    float n3 = __builtin_amdgcn_fmed3f(v, b2, b3);
    float n4 = __builtin_amdgcn_fmed3f(v, b3, b4);
    b0 = n0; b1 = n1; b2 = n2; b3 = n3; b4 = n4;
}

// Scan a CH-candidate LDS chunk (LDS-local base tl, global index base tg) for
// TWO queries per lane. One broadcast ds_read_b128 serves 128 pairs; 4-deep
// A/B ping-pong (r10/r13-proven, no spill).
template<bool SELF, bool PACK>
__device__ __forceinline__ void scanLDS2(const float4* lc, int tl, int tg,
                                         float a0, float b0c, float c0, int q0,
                                         float a1, float b1c, float c1, int q1,
                                         float& x0, float& x1, float& x2,
                                         float& x3, float& x4,
                                         float& y0, float& y1, float& y2,
                                         float& y3, float& y4) {
    float4 A[4], B[4];
#pragma unroll
    for (int j = 0; j < 4; ++j) A[j] = lc[tl + j];

    for (int t0 = 0; t0 < CH; t0 += 8) {
#pragma unroll
        for (int j = 0; j < 4; ++j) B[j] = lc[tl + t0 + 4 + j];
#pragma unroll
        for (int j = 0; j < 4; ++j) {
            proc1<SELF, PACK>(A[j], tg + t0 + j, q0, a0, b0c, c0, x0, x1, x2, x3, x4);
            proc1<SELF, PACK>(A[j], tg + t0 + j, q1, a1, b1c, c1, y0, y1, y2, y3, y4);
        }
        if (t0 + 8 < CH) {
#pragma unroll
            for (int j = 0; j < 4; ++j) A[j] = lc[tl + t0 + 8 + j];
        }
#pragma unroll
        for (int j = 0; j < 4; ++j) {
            proc1<SELF, PACK>(B[j], tg + t0 + 4 + j, q0, a0, b0c, c0, x0, x1, x2, x3, x4);
            proc1<SELF, PACK>(B[j], tg + t0 + 4 + j, q1, a1, b1c, c1, y0, y1, y2, y3, y4);
        }
    }
}

// Merge two sorted 5-lists -> smallest 5, fully static min/max network
// (no runtime-indexed register arrays -> no scratch). u_k = min(A_k, B_k,
// min_{i+j=k-1} max(A_i,B_j)). Ties: equal packed values impossible across
// disjoint index halves; min on equal scores picks smaller packed = smaller
// index, matching top_k.
__device__ __forceinline__ void merge5(float& a0, float& a1, float& a2,
                                       float& a3, float& a4,
                                       float m0, float m1, float m2,
                                       float m3, float m4) {
    float u0 = fminf(a0, m0);
    float u1 = fminf(fminf(a1, m1), fmaxf(a0, m0));
    float u2 = fminf(fminf(a2, m2), fminf(fmaxf(a0, m1), fmaxf(a1, m0)));
    float u3 = fminf(fminf(a3, m3),
                     fminf(fmaxf(a0, m2), fminf(fmaxf(a1, m1), fmaxf(a2, m0))));
    float u4 = fminf(fminf(a4, m4),
                     fminf(fminf(fmaxf(a0, m3), fmaxf(a1, m2)),
                           fminf(fmaxf(a2, m1), fmaxf(a3, m0))));
    a0 = u0; a1 = u1; a2 = u2; a3 = u3; a4 = u4;
}

// K1: Y_rigid (padded float4 + norm), X padded float4 + norm, rmse/disp
// partials, rot/trans losses.
__global__ void k_prep(const float* __restrict__ Y, const float* __restrict__ X,
                       const float* __restrict__ Rp, const float* __restrict__ tp,
                       const float* __restrict__ Rg, const float* __restrict__ tg,
                       const float* __restrict__ dl,
                       float4* __restrict__ YrP, float4* __restrict__ XP,
                       float* __restrict__ acc) {
    int b = blockIdx.x >> 4;
    int n = ((blockIdx.x & 15) << 8) + threadIdx.x;
    size_t base = ((size_t)b * NN + n) * 3;
    float yx = Y[base + 0], yy = Y[base + 1], yz = Y[base + 2];

    float rp[9], rg[9], tpv[3], tgv[3];
#pragma unroll
    for (int i = 0; i < 9; ++i) { rp[i] = Rp[b * 9 + i]; rg[i] = Rg[b * 9 + i]; }
#pragma unroll
    for (int i = 0; i < 3; ++i) { tpv[i] = tp[b * 3 + i]; tgv[i] = tg[b * 3 + i]; }

    float p[3], dr2 = 0.f;
#pragma unroll
    for (int k = 0; k < 3; ++k) {
        float pv = fmaf(yx, rp[k * 3 + 0], fmaf(yy, rp[k * 3 + 1], fmaf(yz, rp[k * 3 + 2], tpv[k])));
        float gv = fmaf(yx, rg[k * 3 + 0], fmaf(yy, rg[k * 3 + 1], fmaf(yz, rg[k * 3 + 2], tgv[k])));
        p[k] = pv;
        float dd = pv - gv;
        dr2 = fmaf(dd, dd, dr2);
    }
    YrP[(size_t)b * NPAD + n] =
        make_float4(p[0], p[1], p[2], fmaf(p[0], p[0], fmaf(p[1], p[1], p[2] * p[2])));

    float4 xe;
    if (n < MM) {
        size_t xb = ((size_t)b * MM + n) * 3;
        float x0 = X[xb + 0], x1 = X[xb + 1], x2 = X[xb + 2];
        xe = make_float4(x0, x1, x2, fmaf(x0, x0, fmaf(x1, x1, x2 * x2)));
    } else {
        xe = make_float4(0.f, 0.f, 0.f, INFF);
    }
    XP[(size_t)b * NPAD + n] = xe;

    float d0 = dl[base + 0], d1 = dl[base + 1], d2 = dl[base + 2];
    float dsq = d0 * d0 + d1 * d1 + d2 * d2;

    dr2 = waveReduceSum(dr2);
    dsq = waveReduceSum(dsq);
    if ((threadIdx.x & 63) == 0) {
        atomicAdd(&acc[ACC_RMSE + b], dr2);
        atomicAdd(&acc[ACC_DISP], dsq);
    }

    if (threadIdx.x == 0 && (blockIdx.x & 15) == 0) {
        float tr = 0.f;
#pragma unroll
        for (int i = 0; i < 9; ++i) tr += rp[i] * rg[i];
        float c = (tr - 1.f) * 0.5f;
        c = fminf(fmaxf(c, -1.f + 1e-7f), 1.f - 1e-7f);
        float dx = tpv[0] - tgv[0], dy = tpv[1] - tgv[1], dz = tpv[2] - tgv[2];
        atomicAdd(&acc[ACC_ROT], acosf(c));
        atomicAdd(&acc[ACC_TRANS], sqrtf(dx * dx + dy * dy + dz * dz));
    }
}

__device__ void finalize(const float* acc, float* out) {
    float a[ACC_COUNT];
#pragma unroll
    for (int i = 0; i < ACC_COUNT; ++i)
        a[i] = __hip_atomic_load(&acc[i], __ATOMIC_RELAXED, __HIP_MEMORY_SCOPE_AGENT);
    float L_rot = a[ACC_ROT] / BB;
    float L_trans = a[ACC_TRANS] / BB;
    float L_rmse = 0.f;
#pragma unroll
    for (int b = 0; b < BB; ++b) L_rmse += sqrtf(a[ACC_RMSE + b] / NN);
    L_rmse /= BB;
    float L_align = a[ACC_ALIGN] / ((float)BB * NN * KK);
    float L_disp = a[ACC_DISP] / ((float)BB * NN);
    float L_def = a[ACC_DEFORM] / ((float)BB * NN * KK);
    float L_lap = a[ACC_LAP] / ((float)BB * NN);
    float rigid = L_rot + L_trans + L_rmse;
    float nr = L_align + 0.01f * L_disp + 0.1f * L_def + 0.1f * L_lap;
    out[0] = rigid + nr; out[1] = rigid; out[2] = nr;
    out[3] = L_rot; out[4] = L_trans; out[5] = L_rmse;
    out[6] = L_align; out[7] = L_disp; out[8] = L_def; out[9] = L_lap;
}

#define MERGE_STEP(W) { float d = md[W][l][pp##W]; if (d < best) { best = d; bw = W; } }
#define MERGE_ADV()  { pp0 += (bw == 0); pp1 += (bw == 1); pp2 += (bw == 2); pp3 += (bw == 3); \
                       pp4 += (bw == 4); pp5 += (bw == 5); pp6 += (bw == 6); pp7 += (bw == 7); }

// K2: fully fused scan. blockIdx.z = mode (0=align on XP, 1=knn on YrP).
// Loop over 2 halves: stage 2048 cands (32 KB), 8 waves x 256-chunks, Q=2;
// per-half 8-way LDS merge -> static merge5 accumulation in registers;
// epilogue + last-block finalize in-block. No partials, no merge kernel.
__global__ __launch_bounds__(512, 4) void k_scan(const float* __restrict__ Xh,
                                                 const float4* __restrict__ XP,
                                                 const float4* __restrict__ YrP,
                                                 const float* __restrict__ dl,
                                                 float* __restrict__ acc,
                                                 unsigned* __restrict__ doneCnt,
                                                 float* __restrict__ out) {
    __shared__ float4 stage[HSZ];                  // 32 KB candidate stage
    __shared__ float md[NWAVE][QG][6];             // 24 KB merge partials
    int tid = threadIdx.x, wave = tid >> 6, lane = tid & 63;
    int qg = blockIdx.x, b = blockIdx.y, mode = blockIdx.z;
    int q0 = qg * QG + lane, q1 = q0 + 64;

    const float4* cbG = (mode == 0 ? XP : YrP) + (size_t)b * NPAD;

    float qx0, qy0, qz0, qx1, qy1, qz1;
    if (mode == 0) {
        size_t a0 = ((size_t)b * NN + q0) * 3;
        size_t a1 = ((size_t)b * NN + q1) * 3;
        qx0 = Xh[a0 + 0]; qy0 = Xh[a0 + 1]; qz0 = Xh[a0 + 2];
        qx1 = Xh[a1 + 0]; qy1 = Xh[a1 + 1]; qz1 = Xh[a1 + 2];
    } else {
        float4 p0 = cbG[q0], p1 = cbG[q1];
        qx0 = p0.x; qy0 = p0.y; qz0 = p0.z;
        qx1 = p1.x; qy1 = p1.y; qz1 = p1.z;
    }

    float f0 = INFF, f1 = INFF, f2 = INFF, f3 = INFF, f4 = INFF;  // running top-5

#pragma unroll
    for (int half = 0; half < 2; ++half) {
        __syncthreads();                           // md reads of prev half done
#pragma unroll
        for (int i = 0; i < HSZ / 512; ++i)
            stage[tid + i * 512] = cbG[half * HSZ + tid + i * 512];
        __syncthreads();

        float x0 = INFF, x1 = INFF, x2 = INFF, x3 = INFF, x4 = INFF;
        float y0 = INFF, y1 = INFF, y2 = INFF, y3 = INFF, y4 = INFF;
        int tl = wave * CH;
        int tg = half * HSZ + tl;
        bool hasSelf = (mode == 1) && (half == (qg >> 4)) && (wave == ((qg >> 1) & 7));
        if (mode == 0) {
            scanLDS2<false, false>(stage, tl, tg,
                                   -2.f * qx0, -2.f * qy0, -2.f * qz0, 0,
                                   -2.f * qx1, -2.f * qy1, -2.f * qz1, 0,
                                   x0, x1, x2, x3, x4, y0, y1, y2, y3, y4);
        } else if (hasSelf) {
            scanLDS2<true, true>(stage, tl, tg,
                                 -2.f * qx0, -2.f * qy0, -2.f * qz0, q0,
                                 -2.f * qx1, -2.f * qy1, -2.f * qz1, q1,
                                 x0, x1, x2, x3, x4, y0, y1, y2, y3, y4);
        } else {
            scanLDS2<false, true>(stage, tl, tg,
                                  -2.f * qx0, -2.f * qy0, -2.f * qz0, q0,
                                  -2.f * qx1, -2.f * qy1, -2.f * qz1, q1,
                                  x0, x1, x2, x3, x4, y0, y1, y2, y3, y4);
        }

        md[wave][lane][0] = x0; md[wave][lane][1] = x1; md[wave][lane][2] = x2;
        md[wave][lane][3] = x3; md[wave][lane][4] = x4; md[wave][lane][5] = INFF;
        md[wave][lane + 64][0] = y0; md[wave][lane + 64][1] = y1;
        md[wave][lane + 64][2] = y2; md[wave][lane + 64][3] = y3;
        md[wave][lane + 64][4] = y4; md[wave][lane + 64][5] = INFF;
        __syncthreads();

        if (tid < QG) {
            int l = tid;
            int pp0 = 0, pp1 = 0, pp2 = 0, pp3 = 0, pp4 = 0, pp5 = 0, pp6 = 0, pp7 = 0;
            float m5[KK];
#pragma unroll
            for (int k = 0; k < KK; ++k) {
                float best = INFF; int bw = 0;
                MERGE_STEP(0) MERGE_STEP(1) MERGE_STEP(2) MERGE_STEP(3)
                MERGE_STEP(4) MERGE_STEP(5) MERGE_STEP(6) MERGE_STEP(7)
                m5[k] = best;
                MERGE_ADV()
            }
            merge5(f0, f1, f2, f3, f4, m5[0], m5[1], m5[2], m5[3], m5[4]);
        }
    }

    // ---- epilogue (tid < QG owns query q) ----
    if (tid < QG) {
        int l = tid;
        int q = qg * QG + l;
        if (mode == 0) {
            size_t a0 = ((size_t)b * NN + q) * 3;
            float qx = Xh[a0 + 0], qy = Xh[a0 + 1], qz = Xh[a0 + 2];
            float qn = fmaf(qx, qx, fmaf(qy, qy, qz * qz));
            float s = fmaxf(f0 + qn, 0.f) + fmaxf(f1 + qn, 0.f) + fmaxf(f2 + qn, 0.f)
                    + fmaxf(f3 + qn, 0.f) + fmaxf(f4 + qn, 0.f);
            s = waveReduceSum(s);
            if ((l & 63) == 0) atomicAdd(&acc[ACC_ALIGN], s);
        } else {
            int si[KK];
            si[0] = (int)(__float_as_uint(f0) & 0xFFFu);
            si[1] = (int)(__float_as_uint(f1) & 0xFFFu);
            si[2] = (int)(__float_as_uint(f2) & 0xFFFu);
            si[3] = (int)(__float_as_uint(f3) & 0xFFFu);
            si[4] = (int)(__float_as_uint(f4) & 0xFFFu);

            float4 qp = cbG[q];
            const float* xh = Xh + (size_t)b * NN * 3;
            const float* dlb = dl + (size_t)b * NN * 3;
            float xnx = xh[q * 3 + 0], xny = xh[q * 3 + 1], xnz = xh[q * 3 + 2];
            float dnx = dlb[q * 3 + 0], dny = dlb[q * 3 + 1], dnz = dlb[q * 3 + 2];

            float def = 0.f, sx = 0.f, sy = 0.f, sz = 0.f;
#pragma unroll
            for (int k = 0; k < KK; ++k) {
                int n = si[k];
                float4 yj = cbG[n];                // L2-resident gather
                float ex = (xh[n * 3 + 0] - xnx) - (yj.x - qp.x);
                float ey = (xh[n * 3 + 1] - xny) - (yj.y - qp.y);
                float ez = (xh[n * 3 + 2] - xnz) - (yj.z - qp.z);
                def += ex * ex + ey * ey + ez * ez;
                sx += dlb[n * 3 + 0]; sy += dlb[n * 3 + 1]; sz += dlb[n * 3 + 2];
            }
            float lx = dnx - sx / 5.f, ly = dny - sy / 5.f, lz = dnz - sz / 5.f;
            float lap = lx * lx + ly * ly + lz * lz;

            def = waveReduceSum(def);
            lap = waveReduceSum(lap);
            if ((l & 63) == 0) {
                atomicAdd(&acc[ACC_DEFORM], def);
                atomicAdd(&acc[ACC_LAP], lap);
            }
        }
    }
    __syncthreads();
    if (tid == 0) {
        __threadfence();
        unsigned t = __hip_atomic_fetch_add(doneCnt, 1u, __ATOMIC_ACQ_REL,
                                            __HIP_MEMORY_SCOPE_AGENT);
        if (t == SCAN_BLOCKS - 1) finalize(acc, out);
    }
}

extern "C" void kernel_launch(void* const* d_in, const int* in_sizes, int n_in,
                              void* d_out, int out_size, void* d_ws, size_t ws_size,
                              hipStream_t stream) {
    const float* Y  = (const float*)d_in[0];
    const float* X  = (const float*)d_in[1];
    const float* Rp = (const float*)d_in[2];
    const float* tp = (const float*)d_in[3];
    const float* Rg = (const float*)d_in[4];
    const float* tg = (const float*)d_in[5];
    const float* Xh = (const float*)d_in[6];
    const float* dl = (const float*)d_in[7];
    float* out = (float*)d_out;

    float*    acc     = (float*)d_ws;                            // 14 floats
    unsigned* doneCnt = (unsigned*)((char*)d_ws + 64);
    float4*   YrP     = (float4*)((char*)d_ws + 512);            // 512 KB
    float4*   XP      = YrP + (size_t)BB * NPAD;                 // 512 KB

    hipMemsetAsync(d_ws, 0, 512, stream);
    hipLaunchKernelGGL(k_prep, dim3(BB * NN / 256), dim3(256), 0, stream,
                       Y, X, Rp, tp, Rg, tg, dl, YrP, XP, acc);
    hipLaunchKernelGGL(k_scan, dim3(NN / QG, BB, 2), dim3(512), 0, stream,
                       Xh, XP, YrP, dl, acc, doneCnt, out);
}